// Round 1
// baseline (376.078 us; speedup 1.0000x reference)
//
#include <hip/hip_runtime.h>

#define NSIDE 1024

typedef __attribute__((ext_vector_type(8))) short short8;
typedef __attribute__((ext_vector_type(4))) float floatx4;

__device__ __forceinline__ unsigned short f2bf(float f) {
    unsigned u = __float_as_uint(f);
    unsigned r = (u + 0x7fffu + ((u >> 16) & 1u)) >> 16;
    return (unsigned short)r;
}

__device__ __forceinline__ short8 cvt8(const float* p) {
    floatx4 a = *(const floatx4*)p;
    floatx4 b = *(const floatx4*)(p + 4);
    short8 v;
    v[0] = (short)f2bf(a[0]); v[1] = (short)f2bf(a[1]);
    v[2] = (short)f2bf(a[2]); v[3] = (short)f2bf(a[3]);
    v[4] = (short)f2bf(b[0]); v[5] = (short)f2bf(b[1]);
    v[6] = (short)f2bf(b[2]); v[7] = (short)f2bf(b[3]);
    return v;
}

// ---------------- pass 1a: col_pool[r] = mean_c input[r*N+c], diag row, global sums
__global__ __launch_bounds__(256) void colpool_kernel(const float* __restrict__ in,
        float* __restrict__ col_pool, float* __restrict__ diagbuf,
        float* __restrict__ all_sum, float* __restrict__ diag_sum) {
    __shared__ float red[256];
    int r = blockIdx.x;
    int t = threadIdx.x;
    int k = t & 63;
    int c0 = t >> 6;
    const float* base = in + ((size_t)r << 16);
    float acc = 0.f;
    #pragma unroll 4
    for (int c = c0; c < NSIDE; c += 4)
        acc += base[c * 64 + k];
    red[t] = acc;
    __syncthreads();
    if (t < 64) {
        float s = red[t] + red[64 + t] + red[128 + t] + red[192 + t];
        col_pool[r * 64 + t] = s * (1.f / 1024.f);
        atomicAdd(&all_sum[t], s);
        float d = base[r * 64 + t];          // input[(r*N+r)*64 + t]
        diagbuf[r * 64 + t] = d;
        atomicAdd(&diag_sum[t], d);
    }
}

// ---------------- pass 1b: row_pool partials over r-chunks (coalesced 1KB lines)
__global__ __launch_bounds__(256) void rowpool_part_kernel(const float* __restrict__ in,
        float* __restrict__ rowpart) {
    int j = blockIdx.x * 256 + threadIdx.x;       // j = c*64 + k  in [0,65536)
    int r0 = blockIdx.y * 128;
    const float* p = in + (size_t)r0 * 65536 + j;
    float acc = 0.f;
    #pragma unroll 4
    for (int r = 0; r < 128; ++r)
        acc += p[(size_t)r * 65536];
    rowpart[blockIdx.y * 65536 + j] = acc;
}

__global__ __launch_bounds__(256) void rowpool_reduce_kernel(const float* __restrict__ rowpart,
        float* __restrict__ row_pool) {
    int j = blockIdx.x * 256 + threadIdx.x;
    float s = 0.f;
    #pragma unroll
    for (int y = 0; y < 8; ++y) s += rowpart[y * 65536 + j];
    row_pool[j] = s * (1.f / 1024.f);
}

// ---------------- W0/W1 transposed -> bf16 bits: wt[n*64+k] = bf16(W[k*64+n])
__global__ __launch_bounds__(256) void wconv_kernel(const float* __restrict__ wts,
        unsigned short* __restrict__ w0t, unsigned short* __restrict__ w1t) {
    int idx = blockIdx.x * 256 + threadIdx.x;     // 4096
    int n = idx >> 6, k = idx & 63;
    w0t[idx] = f2bf(wts[k * 64 + n]);
    w1t[idx] = f2bf(wts[4096 + k * 64 + n]);
}

// ---------------- A[c], B[r], Dg[i] tables (fp32 exact, trivial FLOPs)
__global__ __launch_bounds__(64) void abd_kernel(const float* __restrict__ W,
        const float* __restrict__ col_pool, const float* __restrict__ row_pool,
        const float* __restrict__ diagbuf, const float* __restrict__ all_sum,
        const float* __restrict__ diag_sum,
        float* __restrict__ Ab, float* __restrict__ Bb, float* __restrict__ Dgb) {
    __shared__ float rp[64], cp[64], dv[64], ap[64], dp[64];
    int i = blockIdx.x, o = threadIdx.x;
    rp[o] = row_pool[i * 64 + o];
    cp[o] = col_pool[i * 64 + o];
    dv[o] = diagbuf[i * 64 + o];
    ap[o] = all_sum[o] * (1.f / 1048576.f);
    dp[o] = diag_sum[o] * (1.f / 1024.f);
    __syncthreads();
    float aA = 0.f, aB = 0.f, aD = 0.f;
    #pragma unroll 4
    for (int k = 0; k < 64; ++k) {
        int ko = k * 64 + o;
        aA += rp[k] * W[3 * 4096 + ko] + cp[k] * W[6 * 4096 + ko]
            + dv[k] * W[13 * 4096 + ko] + ap[k] * W[7 * 4096 + ko]
            + dp[k] * W[12 * 4096 + ko];
        aB += rp[k] * W[4 * 4096 + ko] + cp[k] * W[5 * 4096 + ko]
            + dv[k] * W[14 * 4096 + ko];
        aD += dv[k] * W[2 * 4096 + ko] + rp[k] * W[10 * 4096 + ko]
            + cp[k] * W[11 * 4096 + ko] + dp[k] * W[8 * 4096 + ko]
            + ap[k] * W[9 * 4096 + ko];
    }
    Ab[i * 64 + o] = aA;
    Bb[i * 64 + o] = aB;
    Dgb[i * 64 + o] = aD;
}

// ---------------- main: out[s] = in[s]@W0 + in[trans]@W1 + A[c] + B[r] + (r==c)?Dg[r]
__global__ __launch_bounds__(256) void main_kernel(const float* __restrict__ in,
        const unsigned short* __restrict__ w0t, const unsigned short* __restrict__ w1t,
        const float* __restrict__ Ab, const float* __restrict__ Bb,
        const float* __restrict__ Dgb, float* __restrict__ out) {
    int tid = threadIdx.x;
    int lane = tid & 63, wave = tid >> 6;
    int lrow = lane & 15;
    int koff = (lane >> 4) * 8;          // k sub-offset within a K=32 fragment
    int blk = blockIdx.x;
    int r = blk >> 3;                     // 128 s-rows per block, 8 blocks per r
    int c0 = (blk & 7) << 7;
    size_t s0 = (size_t)blk << 7;

    // W fragments, register resident: B-operand layout col=lane&15, k=(lane>>4)*8+i
    short8 bw0[2][4], bw1[2][4];
    #pragma unroll
    for (int kg = 0; kg < 2; ++kg)
        #pragma unroll
        for (int nt = 0; nt < 4; ++nt) {
            int off = (nt * 16 + lrow) * 64 + kg * 32 + koff;
            bw0[kg][nt] = *(const short8*)(w0t + off);
            bw1[kg][nt] = *(const short8*)(w1t + off);
        }
    float brow[4];
    #pragma unroll
    for (int nt = 0; nt < 4; ++nt) brow[nt] = Bb[r * 64 + nt * 16 + lrow];

    #pragma unroll
    for (int mt = 0; mt < 2; ++mt) {
        int rowbase = wave * 32 + mt * 16;
        short8 ao[2], at[2];
        #pragma unroll
        for (int kg = 0; kg < 2; ++kg) {
            const float* po = in + (s0 + rowbase + lrow) * 64 + kg * 32 + koff;
            ao[kg] = cvt8(po);
            int cl = c0 + rowbase + lrow;
            const float* pt = in + ((size_t)cl * 1024 + (size_t)r) * 64 + kg * 32 + koff;
            at[kg] = cvt8(pt);
        }
        floatx4 acc[4];
        #pragma unroll
        for (int nt = 0; nt < 4; ++nt) acc[nt] = (floatx4){0.f, 0.f, 0.f, 0.f};
        #pragma unroll
        for (int nt = 0; nt < 4; ++nt) {
            acc[nt] = __builtin_amdgcn_mfma_f32_16x16x32_bf16(ao[0], bw0[0][nt], acc[nt], 0, 0, 0);
            acc[nt] = __builtin_amdgcn_mfma_f32_16x16x32_bf16(ao[1], bw0[1][nt], acc[nt], 0, 0, 0);
            acc[nt] = __builtin_amdgcn_mfma_f32_16x16x32_bf16(at[0], bw1[0][nt], acc[nt], 0, 0, 0);
            acc[nt] = __builtin_amdgcn_mfma_f32_16x16x32_bf16(at[1], bw1[1][nt], acc[nt], 0, 0, 0);
        }
        // D layout: row=(lane>>4)*4+j, col=lane&15
        int rloc = rowbase + (lane >> 4) * 4;
        #pragma unroll
        for (int j = 0; j < 4; ++j) {
            int cj = c0 + rloc + j;
            size_t srow = s0 + rloc + j;
            bool isd = (cj == r);
            #pragma unroll
            for (int nt = 0; nt < 4; ++nt) {
                int n = nt * 16 + lrow;
                float v = acc[nt][j] + Ab[cj * 64 + n] + brow[nt];
                if (isd) v += Dgb[r * 64 + n];
                out[srow * 64 + n] = v;
            }
        }
    }
}

extern "C" void kernel_launch(void* const* d_in, const int* in_sizes, int n_in,
                              void* d_out, int out_size, void* d_ws, size_t ws_size,
                              hipStream_t stream) {
    const float* in  = (const float*)d_in[0];
    const float* wts = (const float*)d_in[1];
    float* out = (float*)d_out;
    float* ws = (float*)d_ws;

    float* col_pool = ws;                   // 65536
    float* row_pool = ws + 65536;           // 65536
    float* diagbuf  = ws + 131072;          // 65536
    float* all_sum  = ws + 196608;          // 64
    float* diag_sum = ws + 196672;          // 64
    float* Ab       = ws + 196736;          // 65536
    float* Bb       = ws + 262272;          // 65536
    float* Dgb      = ws + 327808;          // 65536
    unsigned short* w0t = (unsigned short*)(ws + 393344);  // 4096 u16
    unsigned short* w1t = (unsigned short*)(ws + 395392);  // 4096 u16
    float* rowpart  = ws + 397440;          // 8*65536

    hipMemsetAsync((void*)all_sum, 0, 128 * sizeof(float), stream);

    colpool_kernel<<<1024, 256, 0, stream>>>(in, col_pool, diagbuf, all_sum, diag_sum);
    rowpool_part_kernel<<<dim3(256, 8), 256, 0, stream>>>(in, rowpart);
    rowpool_reduce_kernel<<<256, 256, 0, stream>>>(rowpart, row_pool);
    wconv_kernel<<<16, 256, 0, stream>>>(wts, w0t, w1t);
    abd_kernel<<<1024, 64, 0, stream>>>(wts, col_pool, row_pool, diagbuf,
                                        all_sum, diag_sum, Ab, Bb, Dgb);
    main_kernel<<<8192, 256, 0, stream>>>(in, w0t, w1t, Ab, Bb, Dgb, out);
}

// Round 2
// 264.739 us; speedup vs baseline: 1.4206x; 1.4206x over previous
//
#include <hip/hip_runtime.h>

typedef __attribute__((ext_vector_type(8))) short short8;
typedef __attribute__((ext_vector_type(4))) float floatx4;

__device__ __forceinline__ unsigned short f2bf(float f) {
    unsigned u = __float_as_uint(f);
    unsigned r = (u + 0x7fffu + ((u >> 16) & 1u)) >> 16;
    return (unsigned short)r;
}

__device__ __forceinline__ short8 cvt8(const float* p) {
    floatx4 a = *(const floatx4*)p;
    floatx4 b = *(const floatx4*)(p + 4);
    short8 v;
    v[0] = (short)f2bf(a[0]); v[1] = (short)f2bf(a[1]);
    v[2] = (short)f2bf(a[2]); v[3] = (short)f2bf(a[3]);
    v[4] = (short)f2bf(b[0]); v[5] = (short)f2bf(b[1]);
    v[6] = (short)f2bf(b[2]); v[7] = (short)f2bf(b[3]);
    return v;
}

// =============== fused sweep: rowpartY (row-sum partials) + colsum (atomics)
// grid (64 c-blocks of 16, 8 r-blocks of 128), 256 thr
__global__ __launch_bounds__(256) void sweep_kernel(const float* __restrict__ in,
        float* __restrict__ rowpartY, float* __restrict__ colsum) {
    int t = threadIdx.x;
    int k = t & 63;
    int rg = t >> 6;                       // 4 r-phases
    int c0 = blockIdx.x * 16;
    int r0 = blockIdx.y * 128;
    const float* base = in + ((size_t)(r0 + rg) << 16) + (size_t)c0 * 64 + k;
    float rowacc[16];
    float colacc[32];
    #pragma unroll
    for (int c = 0; c < 16; ++c) rowacc[c] = 0.f;
    #pragma unroll 2
    for (int i = 0; i < 32; ++i) {
        const float* p = base + ((size_t)i << 18);   // 4 rows * 65536 floats
        float cv = 0.f;
        #pragma unroll
        for (int c = 0; c < 16; ++c) {
            float v = p[c * 64];
            rowacc[c] += v;
            cv += v;
        }
        colacc[i] = cv;
    }
    #pragma unroll 4
    for (int i = 0; i < 32; ++i)
        atomicAdd(&colsum[(size_t)(r0 + rg + 4 * i) * 64 + k], colacc[i]);
    __shared__ float red[4][16][64];
    #pragma unroll
    for (int c = 0; c < 16; ++c) red[rg][c][k] = rowacc[c];
    __syncthreads();
    #pragma unroll
    for (int q = 0; q < 4; ++q) {
        int p2 = q * 256 + t;
        int c = p2 >> 6, kk = p2 & 63;
        float s = red[0][c][kk] + red[1][c][kk] + red[2][c][kk] + red[3][c][kk];
        rowpartY[(size_t)blockIdx.y * 65536 + (size_t)(c0 + c) * 64 + kk] = s;
    }
}

// =============== row_pool/col_pool finalize
__global__ __launch_bounds__(256) void rowfin_kernel(const float* __restrict__ rowpartY,
        const float* __restrict__ colsum, float* __restrict__ row_pool,
        float* __restrict__ col_pool) {
    int j = blockIdx.x * 256 + threadIdx.x;
    float s = 0.f;
    #pragma unroll
    for (int y = 0; y < 8; ++y) s += rowpartY[(size_t)y * 65536 + j];
    row_pool[j] = s * (1.f / 1024.f);
    col_pool[j] = colsum[j] * (1.f / 1024.f);
}

// =============== allpart: partial sums of colsum over r  (64 blocks x 16 r)
__global__ __launch_bounds__(256) void allpart_kernel(const float* __restrict__ colsum,
        float* __restrict__ allpart) {
    int t = threadIdx.x, k = t & 63, rl = t >> 6;
    int b = blockIdx.x;
    float s = 0.f;
    #pragma unroll
    for (int u = 0; u < 4; ++u)
        s += colsum[(size_t)(b * 16 + rl + 4 * u) * 64 + k];
    __shared__ float red[4][64];
    red[rl][k] = s;
    __syncthreads();
    if (t < 64)
        allpart[b * 64 + t] = red[0][t] + red[1][t] + red[2][t] + red[3][t];
}

// =============== diag extraction + partials (256 blocks x 4 i)
__global__ __launch_bounds__(256) void diag_kernel(const float* __restrict__ in,
        float* __restrict__ diagbuf, float* __restrict__ diagpart) {
    int t = threadIdx.x, k = t & 63, il = t >> 6;
    int i = blockIdx.x * 4 + il;
    float v = in[(size_t)i * 1025 * 64 + k];
    diagbuf[i * 64 + k] = v;
    __shared__ float red[4][64];
    red[il][k] = v;
    __syncthreads();
    if (t < 64)
        diagpart[blockIdx.x * 64 + t] = red[0][t] + red[1][t] + red[2][t] + red[3][t];
}

// =============== final tiny reduce: all_sum (64 rows), diag_sum (256 rows)
__global__ __launch_bounds__(256) void finB_kernel(const float* __restrict__ allpart,
        const float* __restrict__ diagpart, float* __restrict__ all_sum,
        float* __restrict__ diag_sum) {
    int t = threadIdx.x, k = t & 63, rg = t >> 6;
    float sa = 0.f, sd = 0.f;
    for (int b = rg; b < 64; b += 4) sa += allpart[b * 64 + k];
    for (int b = rg; b < 256; b += 4) sd += diagpart[b * 64 + k];
    __shared__ float red[2][4][64];
    red[0][rg][k] = sa;
    red[1][rg][k] = sd;
    __syncthreads();
    if (t < 64) {
        all_sum[t]  = red[0][0][t] + red[0][1][t] + red[0][2][t] + red[0][3][t];
        diag_sum[t] = red[1][0][t] + red[1][1][t] + red[1][2][t] + red[1][3][t];
    }
}

// =============== W0/W1 transposed -> bf16 bits
__global__ __launch_bounds__(256) void wconv_kernel(const float* __restrict__ wts,
        unsigned short* __restrict__ w0t, unsigned short* __restrict__ w1t) {
    int idx = blockIdx.x * 256 + threadIdx.x;
    int n = idx >> 6, k = idx & 63;
    w0t[idx] = f2bf(wts[k * 64 + n]);
    w1t[idx] = f2bf(wts[4096 + k * 64 + n]);
}

// =============== A[c], B[r], Dg[i] tables (fp32)
__global__ __launch_bounds__(64) void abd_kernel(const float* __restrict__ W,
        const float* __restrict__ col_pool, const float* __restrict__ row_pool,
        const float* __restrict__ diagbuf, const float* __restrict__ all_sum,
        const float* __restrict__ diag_sum,
        float* __restrict__ Ab, float* __restrict__ Bb, float* __restrict__ Dgb) {
    __shared__ float rp[64], cp[64], dv[64], ap[64], dp[64];
    int i = blockIdx.x, o = threadIdx.x;
    rp[o] = row_pool[i * 64 + o];
    cp[o] = col_pool[i * 64 + o];
    dv[o] = diagbuf[i * 64 + o];
    ap[o] = all_sum[o] * (1.f / 1048576.f);
    dp[o] = diag_sum[o] * (1.f / 1024.f);
    __syncthreads();
    float aA = 0.f, aB = 0.f, aD = 0.f;
    #pragma unroll 4
    for (int k = 0; k < 64; ++k) {
        int ko = k * 64 + o;
        aA += rp[k] * W[3 * 4096 + ko] + cp[k] * W[6 * 4096 + ko]
            + dv[k] * W[13 * 4096 + ko] + ap[k] * W[7 * 4096 + ko]
            + dp[k] * W[12 * 4096 + ko];
        aB += rp[k] * W[4 * 4096 + ko] + cp[k] * W[5 * 4096 + ko]
            + dv[k] * W[14 * 4096 + ko];
        aD += dv[k] * W[2 * 4096 + ko] + rp[k] * W[10 * 4096 + ko]
            + cp[k] * W[11 * 4096 + ko] + dp[k] * W[8 * 4096 + ko]
            + ap[k] * W[9 * 4096 + ko];
    }
    Ab[i * 64 + o] = aA;
    Bb[i * 64 + o] = aB;
    Dgb[i * 64 + o] = aD;
}

// =============== main paired-tile kernel: 2080 blocks (upper triangle of 64x64 tiles)
__global__ __launch_bounds__(256) void main_kernel(const float* __restrict__ in,
        const unsigned short* __restrict__ w0t, const unsigned short* __restrict__ w1t,
        const float* __restrict__ Ab, const float* __restrict__ Bb,
        const float* __restrict__ Dgb, float* __restrict__ out) {
    __shared__ short lds[32768];          // 2 tiles * 256 rows * 64 bf16 (swizzled)

    int t = threadIdx.x;
    int lane = t & 63, w = t >> 6;
    int lrow = lane & 15, lhi = lane >> 4;

    // triangular decode
    int p = blockIdx.x;
    float fb = (129.0f - sqrtf(129.0f * 129.0f - 8.0f * (float)p)) * 0.5f;
    int bi = (int)fb;
    while (bi > 0 && bi * (129 - bi) / 2 > p) --bi;
    while ((bi + 1) * (129 - (bi + 1)) / 2 <= p) ++bi;
    int bj = bi + (p - bi * (129 - bi) / 2);
    int r0 = bi * 16, c0 = bj * 16;

    // W fragments (register-resident)
    short8 bw0[2][4], bw1[2][4];
    #pragma unroll
    for (int kg = 0; kg < 2; ++kg)
        #pragma unroll
        for (int nt = 0; nt < 4; ++nt) {
            int off = (nt * 16 + lrow) * 64 + kg * 32 + lhi * 8;
            bw0[kg][nt] = *(const short8*)(w0t + off);
            bw1[kg][nt] = *(const short8*)(w1t + off);
        }

    // stage both tiles: thread t handles (j = (t&127)>>3, g = t&7), i = 2q + (t>>7)
    int sj = (t & 127) >> 3;
    int sg = t & 7;
    int shalf = t >> 7;
    #pragma unroll
    for (int sel = 0; sel < 2; ++sel) {
        int R = sel ? c0 : r0;
        int C = sel ? r0 : c0;
        #pragma unroll
        for (int q = 0; q < 8; ++q) {
            int i = 2 * q + shalf;
            const float* src = in + (((size_t)(R + i) << 10) + (C + sj)) * 64 + sg * 8;
            short8 v = cvt8(src);
            int row = i * 16 + sj;
            int wg = sg ^ ((row ^ (row >> 4)) & 7);
            *(short8*)(lds + sel * 16384 + row * 64 + wg * 8) = v;
        }
    }
    __syncthreads();

    // compute: wave w does rows [w*64, w*64+64) of each out-tile
    #pragma unroll
    for (int sel = 0; sel < 2; ++sel) {
        int selb = sel * 16384;
        int othb = (sel ^ 1) * 16384;
        int rbase = sel ? c0 : r0;
        int cbase = sel ? r0 : c0;
        #pragma unroll
        for (int mf = 0; mf < 4; ++mf) {
            int I = w * 4 + mf;
            int mrow = I * 16 + lrow;
            int swzm = (mrow ^ (mrow >> 4)) & 7;
            int trow = lrow * 16 + I;
            int swzt = (trow ^ (trow >> 4)) & 7;
            short8 ad[2], at2[2];
            #pragma unroll
            for (int kg = 0; kg < 2; ++kg) {
                ad[kg]  = *(const short8*)(lds + selb + mrow * 64 + ((kg * 4 + lhi) ^ swzm) * 8);
                at2[kg] = *(const short8*)(lds + othb + trow * 64 + ((kg * 4 + lhi) ^ swzt) * 8);
            }
            floatx4 acc[4];
            #pragma unroll
            for (int nt = 0; nt < 4; ++nt) acc[nt] = (floatx4){0.f, 0.f, 0.f, 0.f};
            #pragma unroll
            for (int nt = 0; nt < 4; ++nt) {
                acc[nt] = __builtin_amdgcn_mfma_f32_16x16x32_bf16(ad[0],  bw0[0][nt], acc[nt], 0, 0, 0);
                acc[nt] = __builtin_amdgcn_mfma_f32_16x16x32_bf16(ad[1],  bw0[1][nt], acc[nt], 0, 0, 0);
                acc[nt] = __builtin_amdgcn_mfma_f32_16x16x32_bf16(at2[0], bw1[0][nt], acc[nt], 0, 0, 0);
                acc[nt] = __builtin_amdgcn_mfma_f32_16x16x32_bf16(at2[1], bw1[1][nt], acc[nt], 0, 0, 0);
            }
            int ridx = rbase + I;
            float br[4];
            #pragma unroll
            for (int nt = 0; nt < 4; ++nt) br[nt] = Bb[ridx * 64 + nt * 16 + lrow];
            #pragma unroll
            for (int jj = 0; jj < 4; ++jj) {
                int j = lhi * 4 + jj;
                int cidx = cbase + j;
                size_t s = ((size_t)ridx << 10) + cidx;
                bool isd = (ridx == cidx);
                #pragma unroll
                for (int nt = 0; nt < 4; ++nt) {
                    int n = nt * 16 + lrow;
                    float v = acc[nt][jj] + Ab[cidx * 64 + n] + br[nt];
                    if (isd) v += Dgb[ridx * 64 + n];
                    out[s * 64 + n] = v;
                }
            }
        }
    }
}

extern "C" void kernel_launch(void* const* d_in, const int* in_sizes, int n_in,
                              void* d_out, int out_size, void* d_ws, size_t ws_size,
                              hipStream_t stream) {
    const float* in  = (const float*)d_in[0];
    const float* wts = (const float*)d_in[1];
    float* out = (float*)d_out;
    float* ws = (float*)d_ws;

    float* colsum   = ws;                    // 65536 (zeroed each call)
    float* rowpartY = ws + 65536;            // 8*65536 = 524288 (reused for Ab/Bb/Dgb)
    float* Ab       = ws + 65536;            // alias into rowpartY (dead by then)
    float* Bb       = ws + 131072;
    float* Dgb      = ws + 196608;
    float* row_pool = ws + 589824;           // 65536
    float* col_pool = ws + 655360;           // 65536
    float* diagbuf  = ws + 720896;           // 65536
    float* allpart  = ws + 786432;           // 4096
    float* diagpart = ws + 790528;           // 16384
    float* all_sum  = ws + 806912;           // 64
    float* diag_sum = ws + 806976;           // 64
    unsigned short* w0t = (unsigned short*)(ws + 807040);  // 4096 u16
    unsigned short* w1t = (unsigned short*)(ws + 809088);  // 4096 u16

    hipMemsetAsync((void*)colsum, 0, 65536 * sizeof(float), stream);

    sweep_kernel<<<dim3(64, 8), 256, 0, stream>>>(in, rowpartY, colsum);
    rowfin_kernel<<<256, 256, 0, stream>>>(rowpartY, colsum, row_pool, col_pool);
    allpart_kernel<<<64, 256, 0, stream>>>(colsum, allpart);
    diag_kernel<<<256, 256, 0, stream>>>(in, diagbuf, diagpart);
    finB_kernel<<<1, 256, 0, stream>>>(allpart, diagpart, all_sum, diag_sum);
    wconv_kernel<<<16, 256, 0, stream>>>(wts, w0t, w1t);
    abd_kernel<<<1024, 64, 0, stream>>>(wts, col_pool, row_pool, diagbuf,
                                        all_sum, diag_sum, Ab, Bb, Dgb);
    main_kernel<<<2080, 256, 0, stream>>>(in, w0t, w1t, Ab, Bb, Dgb, out);
}